// Round 2
// baseline (463.804 us; speedup 1.0000x reference)
//
#include <hip/hip_runtime.h>
#include <hip/hip_bf16.h>
#include <hip/hip_fp16.h>

#define BB 16
#define LL 2048
#define DD 128
#define SCALE 0.08838834764831845f
// LDS: S/P [16][2048] f16/bf16 = 65536 | mbuf [8][16] f32 = 512 | maxr[16] f32 = 64
#define LDS_BYTES (65536 + 512 + 64)

using short8 = __attribute__((ext_vector_type(8))) short;
using f32x4  = __attribute__((ext_vector_type(4))) float;

#define MFMA(a,b,c) __builtin_amdgcn_mfma_f32_16x16x32_bf16((a),(b),(c),0,0,0)

__device__ __forceinline__ unsigned short f2bf(float x){
  unsigned int u = __float_as_uint(x);
  u += 0x7FFFu + ((u >> 16) & 1u);          // RNE to bf16
  return (unsigned short)(u >> 16);
}
__device__ __forceinline__ float bf2f(unsigned short h){
  return __uint_as_float(((unsigned int)h) << 16);
}
__device__ __forceinline__ unsigned int pkh2(float a, float b){
  unsigned int ua = (unsigned int)__half_as_ushort(__float2half_rn(a));
  unsigned int ub = (unsigned int)__half_as_ushort(__float2half_rn(b));
  return ua | (ub << 16);
}
__device__ __forceinline__ float h2f(unsigned short u){
  return __half2float(__ushort_as_half(u));
}
__device__ __forceinline__ short8 pack8(float4 a, float4 b){
  short8 r;
  r[0]=(short)f2bf(a.x); r[1]=(short)f2bf(a.y); r[2]=(short)f2bf(a.z); r[3]=(short)f2bf(a.w);
  r[4]=(short)f2bf(b.x); r[5]=(short)f2bf(b.y); r[6]=(short)f2bf(b.z); r[7]=(short)f2bf(b.w);
  return r;
}

// ---------- fused prep: mask->bits | K->bf16 hi/lo | V->Vt bf16 ----------
// blocks [0, 8192)        : mask bit-pack (256 MB -> 8 MB)
// blocks [8192, 10240)    : K hi/lo split
// blocks [10240, 14336)   : V transpose to [b][d][k] bf16
__global__ __launch_bounds__(256) void prep_all(
    const float* __restrict__ K, const float* __restrict__ V,
    const int* __restrict__ M,
    unsigned short* __restrict__ kh, unsigned short* __restrict__ kl,
    unsigned short* __restrict__ vt, unsigned int* __restrict__ bm)
{
  __shared__ float t[32][33];
  const int bid = blockIdx.x;
  const int tid = threadIdx.x;
  if (bid < 8192) {
    // each thread: 32 consecutive ints -> one uint32 of bits
    const size_t wi = (size_t)bid * 256 + tid;      // word index, 2^21 total
    const int* mp = M + wi * 32;
    unsigned int wrd = 0;
#pragma unroll
    for (int j = 0; j < 8; ++j) {
      int4 v = *(const int4*)(mp + j*4);
      wrd |= (v.x ? 1u : 0u) << (4*j)
          |  (v.y ? 1u : 0u) << (4*j+1)
          |  (v.z ? 1u : 0u) << (4*j+2)
          |  (v.w ? 1u : 0u) << (4*j+3);
    }
    bm[wi] = wrd;
  } else if (bid < 10240) {
    const size_t i = ((size_t)(bid - 8192) * 256 + tid) * 8;
    float4 a = *(const float4*)(K + i);
    float4 c = *(const float4*)(K + i + 4);
    float v[8] = {a.x,a.y,a.z,a.w,c.x,c.y,c.z,c.w};
    uint4 hv, lv;
    unsigned int H[4], L[4];
#pragma unroll
    for (int j = 0; j < 4; ++j) {
      unsigned short h0 = f2bf(v[2*j]),   h1 = f2bf(v[2*j+1]);
      unsigned short l0 = f2bf(v[2*j]   - bf2f(h0));
      unsigned short l1 = f2bf(v[2*j+1] - bf2f(h1));
      H[j] = (unsigned int)h0 | ((unsigned int)h1 << 16);
      L[j] = (unsigned int)l0 | ((unsigned int)l1 << 16);
    }
    hv.x=H[0]; hv.y=H[1]; hv.z=H[2]; hv.w=H[3];
    lv.x=L[0]; lv.y=L[1]; lv.z=L[2]; lv.w=L[3];
    *(uint4*)(kh + i) = hv;
    *(uint4*)(kl + i) = lv;
  } else {
    const int tt = (bid - 10240) & 255;
    const int b  = (bid - 10240) >> 8;
    const int k0 = (tt >> 2) * 32, d0 = (tt & 3) * 32;
    const int r  = tid >> 3, cc = (tid & 7) * 4;
    float4 x = *(const float4*)(V + ((size_t)b*LL + k0 + r)*DD + d0 + cc);
    t[cc+0][r] = x.x; t[cc+1][r] = x.y; t[cc+2][r] = x.z; t[cc+3][r] = x.w;
    __syncthreads();
    float y0 = t[r][cc], y1 = t[r][cc+1], y2 = t[r][cc+2], y3 = t[r][cc+3];
    uint2 o;
    o.x = (unsigned int)f2bf(y0) | ((unsigned int)f2bf(y1) << 16);
    o.y = (unsigned int)f2bf(y2) | ((unsigned int)f2bf(y3) << 16);
    *(uint2*)(vt + ((size_t)b*DD + d0 + r)*LL + k0 + cc) = o;
  }
}

// ---------- main fused kernel: 1 WG = (batch, 16 q-rows), 8 waves ----------
__global__ __launch_bounds__(512, 4) void attn_main(
    const float* __restrict__ Q, const unsigned int* __restrict__ BM,
    const unsigned short* __restrict__ Kh, const unsigned short* __restrict__ Kl,
    const unsigned short* __restrict__ Vt,
    float* __restrict__ ctxout, float* __restrict__ pout)
{
  extern __shared__ char lds[];                    // S rows: row*4096 + ((2k)^((row&7)<<4))
  float* mbuf = (float*)(lds + 65536);             // [8][16]
  float* maxr = (float*)(lds + 65536 + 512);       // [16]

  const int tid = threadIdx.x;
  const int w = tid >> 6;        // wave 0..7
  const int l = tid & 63;
  const int c = l & 15;          // lane col within 16
  const int g = l >> 4;          // lane group 0..3

  // XCD-aware swizzle: 2048 WGs, 8 XCDs, 2 batches per XCD
  const int bid = blockIdx.x;
  const int xcd = bid & 7, ii = bid >> 3;          // ii 0..255
  const int b  = xcd*2 + (ii >> 7);
  const int q0 = (ii & 127) * 16;

  // ---- Q fragments (B-operand of S^T = K * Q^T): bf16, [dchunk]
  short8 qf[4];
#pragma unroll
  for (int dc = 0; dc < 4; ++dc) {
    const float* qp = Q + ((size_t)b*LL + q0 + c)*DD + dc*32 + g*8;
    float4 u0 = *(const float4*)qp;
    float4 u1 = *(const float4*)(qp + 4);
    qf[dc] = pack8(u0, u1);
  }

  // ---- Phase A: S^T tiles via MFMA, mask(bits)+scale, f16 -> LDS, row-max
  float rmax0 = -3.0e38f;
  const int kcw = w * 256;                         // this wave's k-chunk
  const unsigned int* bmrow = BM + ((size_t)b*LL + q0 + c)*64 + (kcw >> 5);
#pragma unroll 1
  for (int kt2 = 0; kt2 < 8; ++kt2) {
    const unsigned int bw = bmrow[kt2];            // 32 mask bits (L2-resident)
#pragma unroll
    for (int h = 0; h < 2; ++h) {
      const int kt = kt2*2 + h;
      const int krow = kcw + kt*16 + c;
      const unsigned short* khp = Kh + ((size_t)b*LL + krow)*DD + g*8;
      const unsigned short* klp = Kl + ((size_t)b*LL + krow)*DD + g*8;
      short8 ah[4], al[4];
#pragma unroll
      for (int dc = 0; dc < 4; ++dc) {
        ah[dc] = *(const short8*)(khp + dc*32);
        al[dc] = *(const short8*)(klp + dc*32);
      }
      f32x4 acc = {0.f,0.f,0.f,0.f};
#pragma unroll
      for (int dc = 0; dc < 4; ++dc) acc = MFMA(ah[dc], qf[dc], acc);
#pragma unroll
      for (int dc = 0; dc < 4; ++dc) acc = MFMA(al[dc], qf[dc], acc);
      const int kb = kcw + kt*16 + g*4;            // k of acc[0]
      const unsigned int nib = bw >> (h*16 + g*4);
      float s0 = (nib & 1u) ? acc[0]*SCALE : -1e9f;
      float s1 = (nib & 2u) ? acc[1]*SCALE : -1e9f;
      float s2 = (nib & 4u) ? acc[2]*SCALE : -1e9f;
      float s3 = (nib & 8u) ? acc[3]*SCALE : -1e9f;
      rmax0 = fmaxf(rmax0, fmaxf(fmaxf(s0,s1), fmaxf(s2,s3)));
      uint2 pk;
      pk.x = pkh2(s0, s1);
      pk.y = pkh2(s2, s3);
      *(uint2*)(lds + c*4096 + ((kb*2) ^ ((c & 7) << 4))) = pk;
    }
  }
  rmax0 = fmaxf(rmax0, __shfl_xor(rmax0, 16));
  rmax0 = fmaxf(rmax0, __shfl_xor(rmax0, 32));
  if (l < 16) mbuf[w*16 + l] = rmax0;
  __syncthreads();
  if (tid < 16) {
    float m = mbuf[tid];
#pragma unroll
    for (int ww = 1; ww < 8; ++ww) m = fmaxf(m, mbuf[ww*16 + tid]);
    maxr[tid] = m;
  }
  __syncthreads();

  // ---- Phase B+C: per-row softmax; wave w owns rows 2w, 2w+1
#pragma unroll
  for (int rr = 0; rr < 2; ++rr) {
    const int row  = 2*w + rr;
    const float mrow = maxr[row];
    const int swz  = (row & 7) << 4;
    uint4 hv[4];
    float sum = 0.f;
#pragma unroll
    for (int it = 0; it < 4; ++it) {
      const int raw = l*16 + it*1024;              // semantic byte (= 2k)
      hv[it] = *(const uint4*)(lds + row*4096 + (raw ^ swz));
      const unsigned int* wp = (const unsigned int*)&hv[it];
#pragma unroll
      for (int u = 0; u < 4; ++u) {
        unsigned int wd = wp[u];
        sum += __expf(h2f((unsigned short)(wd & 0xFFFFu)) - mrow)
             + __expf(h2f((unsigned short)(wd >> 16))     - mrow);
      }
    }
#pragma unroll
    for (int off = 32; off >= 1; off >>= 1) sum += __shfl_xor(sum, off);
    const float inv = 1.0f / sum;
    float* prow = pout + ((size_t)b*LL + q0 + row)*LL;
#pragma unroll
    for (int it = 0; it < 4; ++it) {
      const int raw = l*16 + it*1024;
      const int kbase = raw >> 1;
      const unsigned int* wp = (const unsigned int*)&hv[it];
      float pv[8];
#pragma unroll
      for (int u = 0; u < 4; ++u) {
        unsigned int wd = wp[u];
        pv[2*u]   = __expf(h2f((unsigned short)(wd & 0xFFFFu)) - mrow) * inv;
        pv[2*u+1] = __expf(h2f((unsigned short)(wd >> 16))     - mrow) * inv;
      }
      float4 o0 = {pv[0],pv[1],pv[2],pv[3]};
      float4 o1 = {pv[4],pv[5],pv[6],pv[7]};
      *(float4*)(prow + kbase)     = o0;
      *(float4*)(prow + kbase + 4) = o1;
      uint4 pb;
      pb.x = (unsigned int)f2bf(pv[0]) | ((unsigned int)f2bf(pv[1]) << 16);
      pb.y = (unsigned int)f2bf(pv[2]) | ((unsigned int)f2bf(pv[3]) << 16);
      pb.z = (unsigned int)f2bf(pv[4]) | ((unsigned int)f2bf(pv[5]) << 16);
      pb.w = (unsigned int)f2bf(pv[6]) | ((unsigned int)f2bf(pv[7]) << 16);
      *(uint4*)(lds + row*4096 + (raw ^ swz)) = pb;   // P as bf16, in place
    }
  }
  __syncthreads();

  // ---- Phase D: context = P (LDS bf16, A-op) * V (Vt global bf16, B-op)
  const int dt = w;                                // wave's 16 d-cols
  const int pswz = (c & 7) << 4;
  const char* pbase = lds + c*4096;
  const unsigned short* vtb = Vt + ((size_t)b*DD + dt*16 + c)*LL;
  f32x4 acc0 = {0.f,0.f,0.f,0.f}, acc1 = {0.f,0.f,0.f,0.f};
#pragma unroll 4
  for (int ks = 0; ks < 64; ks += 2) {
    const int k0 = ks*32 + g*8;
    const int k1 = k0 + 32;
    short8 a0 = *(const short8*)(pbase + ((k0*2) ^ pswz));
    short8 b0 = *(const short8*)(vtb + k0);
    short8 a1 = *(const short8*)(pbase + ((k1*2) ^ pswz));
    short8 b1 = *(const short8*)(vtb + k1);
    acc0 = MFMA(a0, b0, acc0);
    acc1 = MFMA(a1, b1, acc1);
  }
#pragma unroll
  for (int r = 0; r < 4; ++r) {
    const int q = q0 + g*4 + r;
    ctxout[((size_t)b*LL + q)*DD + dt*16 + c] = acc0[r] + acc1[r];
  }
}

// ---------- fallback (ws too small): simple correct version ----------
__global__ __launch_bounds__(256) void attn_naive(
    const float* __restrict__ Q, const float* __restrict__ K,
    const float* __restrict__ V, const int* __restrict__ M,
    float* __restrict__ ctx, float* __restrict__ pout)
{
  const int b = blockIdx.x >> 11;
  const int q = blockIdx.x & (LL-1);
  __shared__ float s[LL];
  __shared__ float red[256];
  const int tid = threadIdx.x;
  const float* qp = Q + ((size_t)b*LL + q)*DD;
  for (int kk = tid; kk < LL; kk += 256) {
    const float* kp = K + ((size_t)b*LL + kk)*DD;
    float a = 0.f;
    for (int d = 0; d < DD; ++d) a += qp[d]*kp[d];
    s[kk] = M[((size_t)b*LL + q)*LL + kk] ? a*SCALE : -1e9f;
  }
  __syncthreads();
  float mx = -3e38f;
  for (int kk = tid; kk < LL; kk += 256) mx = fmaxf(mx, s[kk]);
  red[tid] = mx; __syncthreads();
  for (int o = 128; o >= 1; o >>= 1) {
    if (tid < o) red[tid] = fmaxf(red[tid], red[tid+o]);
    __syncthreads();
  }
  const float mrow = red[0]; __syncthreads();
  float sm = 0.f;
  for (int kk = tid; kk < LL; kk += 256) { float e = __expf(s[kk]-mrow); s[kk] = e; sm += e; }
  red[tid] = sm; __syncthreads();
  for (int o = 128; o >= 1; o >>= 1) {
    if (tid < o) red[tid] += red[tid+o];
    __syncthreads();
  }
  const float inv = 1.0f / red[0]; __syncthreads();
  float* prow = pout + ((size_t)b*LL + q)*LL;
  for (int kk = tid; kk < LL; kk += 256) { s[kk] *= inv; prow[kk] = s[kk]; }
  __syncthreads();
  if (tid < DD) {
    float a = 0.f;
    for (int kk = 0; kk < LL; ++kk) a += s[kk]*V[((size_t)b*LL + kk)*DD + tid];
    ctx[((size_t)b*LL + q)*DD + tid] = a;
  }
}

extern "C" void kernel_launch(void* const* d_in, const int* in_sizes, int n_in,
                              void* d_out, int out_size, void* d_ws, size_t ws_size,
                              hipStream_t stream) {
  (void)in_sizes; (void)n_in; (void)out_size;
  const float* Q = (const float*)d_in[0];
  const float* K = (const float*)d_in[1];
  const float* V = (const float*)d_in[2];
  const int*   M = (const int*)d_in[3];
  float* ctx  = (float*)d_out;
  float* pout = ctx + (size_t)BB*LL*DD;
  const size_t NKV = (size_t)BB*LL*DD;             // 4.19M elems
  const size_t NBM = (size_t)BB*LL*(LL/32);        // 2.10M words
  const size_t WS_NEED = NKV*2*3 + NBM*4;          // Kh+Kl+Vt bf16 + bitmask = 32 MB
  if (ws_size >= WS_NEED) {
    unsigned short* Kh = (unsigned short*)d_ws;
    unsigned short* Kl = Kh + NKV;
    unsigned short* Vt = Kl + NKV;
    unsigned int*   Bm = (unsigned int*)(Vt + NKV);
    hipFuncSetAttribute(reinterpret_cast<const void*>(attn_main),
                        hipFuncAttributeMaxDynamicSharedMemorySize, LDS_BYTES);
    prep_all<<<14336, 256, 0, stream>>>(K, V, M, Kh, Kl, Vt, Bm);
    attn_main<<<2048, 512, LDS_BYTES, stream>>>(Q, Bm, Kh, Kl, Vt, ctx, pout);
  } else {
    attn_naive<<<BB*LL, 256, 0, stream>>>(Q, K, V, M, ctx, pout);
  }
}

// Round 3
// 211.504 us; speedup vs baseline: 2.1929x; 2.1929x over previous
//
#include <hip/hip_runtime.h>
#include <hip/hip_bf16.h>
#include <hip/hip_fp16.h>

#define BB 16
#define LL 2048
#define DD 128
#define SCALE 0.08838834764831845f
#define NT 32        // k-tiles of 64

typedef _Float16 f16x8 __attribute__((ext_vector_type(8)));
typedef float f32x16 __attribute__((ext_vector_type(16)));

#define MFMA32(a,b,c) __builtin_amdgcn_mfma_f32_32x32x16_f16((a),(b),(c),0,0,0)

// LDS map (main): KB 2x16K | VB 2x16K | PB 2x16K | RED 2K | BITS 32K
#define OFF_KB   0
#define OFF_VB   32768
#define OFF_PB   65536
#define OFF_RED  98304
#define OFF_BITS 100352
#define LDS_MAIN 133120

__device__ __forceinline__ f16x8 as_f16x8(uint4 v){
  union { uint4 u; f16x8 h; } x; x.u = v; return x.h;
}
__device__ __forceinline__ unsigned pkf16(float a, float b){
  __half ha = __float2half_rn(a), hb = __float2half_rn(b);
  return (unsigned)__half_as_ushort(ha) | ((unsigned)__half_as_ushort(hb) << 16);
}

// ---------- prep: K -> fp16 swizzled k-major image; V -> fp16 swizzled d-major image ----------
// K image tile (b,t): [k 64][granule 16 x 16B], byte = klocal*256 + ((gd*16)^((klocal&15)<<4))
// V image tile (b,t): [d 128][granule 8 x 16B], byte = d*128 + ((gk*16)^((d&7)<<4)), gk covers k 8*gk..+7
__global__ __launch_bounds__(256) void prep_img(
    const float* __restrict__ K, const float* __restrict__ V,
    unsigned char* __restrict__ kimg, unsigned char* __restrict__ vimg)
{
  __shared__ float t[32][65];
  const int bid = blockIdx.x, tid = threadIdx.x;
  if (bid < 2048) {
    const int G = bid*256 + tid;
    const int b = G >> 15;
    const int k = (G >> 4) & 2047;
    const int gd = G & 15;
    const float* src = K + ((size_t)b*LL + k)*DD + gd*8;
    float4 f0 = *(const float4*)(src);
    float4 f1 = *(const float4*)(src + 4);
    uint4 o;
    o.x = pkf16(f0.x, f0.y); o.y = pkf16(f0.z, f0.w);
    o.z = pkf16(f1.x, f1.y); o.w = pkf16(f1.z, f1.w);
    const size_t base = ((size_t)b*NT + (k>>6))*16384;
    *(uint4*)(kimg + base + (k&63)*256 + ((gd*16) ^ ((k&15)<<4))) = o;
  } else {
    const int t2 = bid - 2048;
    const int b = t2 >> 7;
    const int rem = t2 & 127;
    const int kt = rem >> 2, dt = rem & 3;
    const int k0 = kt*64, d0 = dt*32;
    const int kl = tid >> 2, dq = (tid & 3)*8;
    const float* src = V + ((size_t)b*LL + k0 + kl)*DD + d0 + dq;
    float4 f0 = *(const float4*)(src);
    float4 f1 = *(const float4*)(src + 4);
    t[dq+0][kl] = f0.x; t[dq+1][kl] = f0.y; t[dq+2][kl] = f0.z; t[dq+3][kl] = f0.w;
    t[dq+4][kl] = f1.x; t[dq+5][kl] = f1.y; t[dq+6][kl] = f1.z; t[dq+7][kl] = f1.w;
    __syncthreads();
    const int dl = tid >> 3, kg = tid & 7;
    const int d = d0 + dl;
    uint4 o;
    o.x = pkf16(t[dl][kg*8+0], t[dl][kg*8+1]);
    o.y = pkf16(t[dl][kg*8+2], t[dl][kg*8+3]);
    o.z = pkf16(t[dl][kg*8+4], t[dl][kg*8+5]);
    o.w = pkf16(t[dl][kg*8+6], t[dl][kg*8+7]);
    const size_t base = ((size_t)b*NT + kt)*16384;
    *(uint4*)(vimg + base + d*128 + ((kg*16) ^ ((d&7)<<4))) = o;
  }
}

// round body macros (compile-time BUF/EVEN; rule-#20-safe: no runtime-indexed reg arrays)
#define P1ROUND(R, BUF, NBUF, PREF, EVEN) do { \
  uint4 kn0, kn1; int4 n0, n1, n2, n3; \
  if (PREF) { \
    const unsigned char* nbp = KIMG + imgb + (size_t)((R)+1)*16384; \
    kn0 = *(const uint4*)(nbp + soff); \
    kn1 = *(const uint4*)(nbp + soff + 1024); \
    const int* mp = Mrow + ((R)+1)*64 + moff; \
    n0 = *(const int4*)(mp);    n1 = *(const int4*)(mp+8); \
    n2 = *(const int4*)(mp+16); n3 = *(const int4*)(mp+24); \
  } \
  const char* kb = KB + (BUF)*16384 + krow*256; \
  f32x16 aA, aB; \
  _Pragma("unroll") for (int i=0;i<16;++i){aA[i]=0.f;aB[i]=0.f;} \
  _Pragma("unroll") for (int s=0;s<4;++s){ \
    uint4 af = *(const uint4*)(kb + (((s*2+hi)*16) ^ kswz)); \
    aA = MFMA32(as_f16x8(af), as_f16x8(qf[s]), aA); } \
  _Pragma("unroll") for (int s=4;s<8;++s){ \
    uint4 af = *(const uint4*)(kb + (((s*2+hi)*16) ^ kswz)); \
    aB = MFMA32(as_f16x8(af), as_f16x8(qf[s]), aB); } \
  unsigned bits = (unsigned)(mva0.x!=0)        | ((unsigned)(mva0.y!=0)<<1)  \
                | ((unsigned)(mva0.z!=0)<<2)   | ((unsigned)(mva0.w!=0)<<3)  \
                | ((unsigned)(mva1.x!=0)<<4)   | ((unsigned)(mva1.y!=0)<<5)  \
                | ((unsigned)(mva1.z!=0)<<6)   | ((unsigned)(mva1.w!=0)<<7)  \
                | ((unsigned)(mva2.x!=0)<<8)   | ((unsigned)(mva2.y!=0)<<9)  \
                | ((unsigned)(mva2.z!=0)<<10)  | ((unsigned)(mva2.w!=0)<<11) \
                | ((unsigned)(mva3.x!=0)<<12)  | ((unsigned)(mva3.y!=0)<<13) \
                | ((unsigned)(mva3.z!=0)<<14)  | ((unsigned)(mva3.w!=0)<<15); \
  if (EVEN) bits_lo = bits; \
  else *(unsigned*)(BITSB + ((R)>>1)*2048 + tid*4) = bits_lo | (bits<<16); \
  float sv[16]; \
  _Pragma("unroll") for (int i=0;i<16;++i) sv[i] = ((bits>>i)&1u) ? (aA[i]+aB[i])*SCALE : -1.0e9f; \
  float tmax = sv[0]; \
  _Pragma("unroll") for (int i=1;i<16;++i) tmax = fmaxf(tmax, sv[i]); \
  const float mnew = fmaxf(m_run, tmax); \
  float asum = 0.f; \
  _Pragma("unroll") for (int i=0;i<16;++i) asum += __expf(sv[i]-mnew); \
  s_run = s_run*__expf(m_run-mnew) + asum; m_run = mnew; \
  if (PREF) { \
    char* kd = KB + (NBUF)*16384; \
    *(uint4*)(kd + soff) = kn0; *(uint4*)(kd + soff + 1024) = kn1; \
    mva0=n0; mva1=n1; mva2=n2; mva3=n3; \
  } \
  __syncthreads(); \
} while(0)

#define P2ROUND(R, BUF, NBUF, PREF, EVEN) do { \
  uint4 kn0,kn1,vn0,vn1; \
  if (PREF) { \
    const unsigned char* nk = KIMG + imgb + (size_t)((R)+1)*16384; \
    const unsigned char* nv = VIMG + imgb + (size_t)((R)+1)*16384; \
    kn0 = *(const uint4*)(nk + soff); kn1 = *(const uint4*)(nk + soff + 1024); \
    vn0 = *(const uint4*)(nv + soff); vn1 = *(const uint4*)(nv + soff + 1024); \
  } \
  const char* kb = KB + (BUF)*16384 + krow*256; \
  f32x16 aA, aB; \
  _Pragma("unroll") for (int i=0;i<16;++i){aA[i]=0.f;aB[i]=0.f;} \
  _Pragma("unroll") for (int s=0;s<4;++s){ \
    uint4 af = *(const uint4*)(kb + (((s*2+hi)*16) ^ kswz)); \
    aA = MFMA32(as_f16x8(af), as_f16x8(qf[s]), aA); } \
  _Pragma("unroll") for (int s=4;s<8;++s){ \
    uint4 af = *(const uint4*)(kb + (((s*2+hi)*16) ^ kswz)); \
    aB = MFMA32(as_f16x8(af), as_f16x8(qf[s]), aB); } \
  if (EVEN) bw = *(const unsigned*)(BITSB + ((R)>>1)*2048 + tid*4); \
  const unsigned bits = (EVEN) ? (bw & 0xFFFFu) : (bw >> 16); \
  float pv[16]; \
  _Pragma("unroll") for (int i=0;i<16;++i){ \
    float svv = ((bits>>i)&1u) ? (aA[i]+aB[i])*SCALE : -1.0e9f; \
    pv[i] = __expf(svv - m_f) * inv; } \
  { float* pr = Prow + (R)*64 + sub*32 + hi*4; \
    float4 o; \
    o.x=pv[0]; o.y=pv[1]; o.z=pv[2]; o.w=pv[3];    *(float4*)(pr)    = o; \
    o.x=pv[4]; o.y=pv[5]; o.z=pv[6]; o.w=pv[7];    *(float4*)(pr+8)  = o; \
    o.x=pv[8]; o.y=pv[9]; o.z=pv[10]; o.w=pv[11];  *(float4*)(pr+16) = o; \
    o.x=pv[12]; o.y=pv[13]; o.z=pv[14]; o.w=pv[15]; *(float4*)(pr+24) = o; } \
  { char* pb = PB + (BUF)*16384 + p*4096 + sub*2048; \
    uint2 u; \
    u.x = pkf16(pv[0],pv[1]);   u.y = pkf16(pv[2],pv[3]);   *(uint2*)(pb + c*16 + hi*8) = u; \
    u.x = pkf16(pv[4],pv[5]);   u.y = pkf16(pv[6],pv[7]);   *(uint2*)(pb + (c+32)*16 + hi*8) = u; \
    u.x = pkf16(pv[8],pv[9]);   u.y = pkf16(pv[10],pv[11]); *(uint2*)(pb + 1024 + c*16 + hi*8) = u; \
    u.x = pkf16(pv[12],pv[13]); u.y = pkf16(pv[14],pv[15]); *(uint2*)(pb + 1024 + (c+32)*16 + hi*8) = u; } \
  __syncthreads(); \
  _Pragma("unroll") for (int s2=0;s2<2;++s2){ \
    _Pragma("unroll") for (int k2=0;k2<2;++k2){ \
      const uint4 afr = *(const uint4*)(PB + (BUF)*16384 + p*4096 + s2*2048 + k2*1024 + l*16); \
      const int gix = s2*4 + k2*2 + hi; \
      const int d0v = sub*64 + c; \
      const uint4 b0 = *(const uint4*)(VB + (BUF)*16384 + d0v*128 + ((gix*16) ^ ((d0v&7)<<4))); \
      ctx0 = MFMA32(as_f16x8(afr), as_f16x8(b0), ctx0); \
      const int d1v = sub*64 + 32 + c; \
      const uint4 b1 = *(const uint4*)(VB + (BUF)*16384 + d1v*128 + ((gix*16) ^ ((d1v&7)<<4))); \
      ctx1 = MFMA32(as_f16x8(afr), as_f16x8(b1), ctx1); } } \
  if (PREF) { \
    char* kd = KB + (NBUF)*16384; char* vd = VB + (NBUF)*16384; \
    *(uint4*)(kd + soff) = kn0; *(uint4*)(kd + soff + 1024) = kn1; \
    *(uint4*)(vd + soff) = vn0; *(uint4*)(vd + soff + 1024) = vn1; } \
  __syncthreads(); \
} while(0)

// ---------- main: 1 WG/CU = (batch, 128 q-rows), 8 waves, two passes ----------
__global__ __launch_bounds__(512) void attn_main(
    const float* __restrict__ Q, const int* __restrict__ M,
    const unsigned char* __restrict__ KIMG, const unsigned char* __restrict__ VIMG,
    float* __restrict__ ctxout, float* __restrict__ pout)
{
  extern __shared__ char lds[];
  char* KB = lds + OFF_KB;
  char* VB = lds + OFF_VB;
  char* PB = lds + OFF_PB;
  float* RED = (float*)(lds + OFF_RED);
  char* BITSB = lds + OFF_BITS;

  const int tid = threadIdx.x;
  const int w = tid >> 6, l = tid & 63;
  const int c = l & 31, hi = l >> 5;
  const int p = w >> 1, sub = w & 1;

  const int bid = blockIdx.x;
  const int xcd = bid & 7, jj = bid >> 3;
  const int b = xcd*2 + (jj >> 4);
  const int q0 = (jj & 15) * 128;
  const int qrow = q0 + p*32 + c;

  // Q fragments (fp16), lane c = q-col, hi selects d+8
  uint4 qf[8];
  const float* qp0 = Q + ((size_t)b*LL + qrow)*DD;
#pragma unroll
  for (int s = 0; s < 8; ++s) {
    const float4 f0 = *(const float4*)(qp0 + s*16 + hi*8);
    const float4 f1 = *(const float4*)(qp0 + s*16 + hi*8 + 4);
    uint4 qv;
    qv.x = pkf16(f0.x, f0.y); qv.y = pkf16(f0.z, f0.w);
    qv.z = pkf16(f1.x, f1.y); qv.w = pkf16(f1.z, f1.w);
    qf[s] = qv;
  }

  const size_t imgb = ((size_t)b * NT) * 16384;
  const int soff = w*2048 + l*16;
  const int* Mrow = M + ((size_t)b*LL + qrow)*LL;
  const int moff = sub*32 + hi*4;
  const int krow = sub*32 + c;
  const int kswz = (c & 15) << 4;

  // ---- pass 1 prologue
  {
    uint4 k0 = *(const uint4*)(KIMG + imgb + soff);
    uint4 k1 = *(const uint4*)(KIMG + imgb + soff + 1024);
    *(uint4*)(KB + soff) = k0;
    *(uint4*)(KB + soff + 1024) = k1;
  }
  int4 mva0 = *(const int4*)(Mrow + moff);
  int4 mva1 = *(const int4*)(Mrow + moff + 8);
  int4 mva2 = *(const int4*)(Mrow + moff + 16);
  int4 mva3 = *(const int4*)(Mrow + moff + 24);
  __syncthreads();

  float m_run = -3.0e38f, s_run = 0.0f;
  unsigned bits_lo = 0u;

#pragma unroll 1
  for (int rr = 0; rr < 16; ++rr) {
    const int r0 = rr*2;
    P1ROUND(r0,   0, 1, true,     1);
    P1ROUND(r0+1, 1, 0, (rr<15),  0);
  }

  // combine hi/lo lane halves, then the two k-sub waves of each pair
  {
    float m2 = __shfl_xor(m_run, 32);
    float s2 = __shfl_xor(s_run, 32);
    float mm = fmaxf(m_run, m2);
    s_run = s_run*__expf(m_run-mm) + s2*__expf(m2-mm);
    m_run = mm;
  }
  if (l < 32) {
    RED[((p*2+sub)*32 + c)*2]   = m_run;
    RED[((p*2+sub)*32 + c)*2+1] = s_run;
  }
  __syncthreads();
  float m_f, inv;
  {
    float mo = RED[((p*2+(1-sub))*32 + c)*2];
    float so = RED[((p*2+(1-sub))*32 + c)*2+1];
    float mm = fmaxf(m_run, mo);
    float st = s_run*__expf(m_run-mm) + so*__expf(mo-mm);
    m_f = mm;
    inv = 1.0f / st;
  }
  __syncthreads();

  // ---- pass 2 prologue: stage K,V tile 0
  {
    uint4 k0 = *(const uint4*)(KIMG + imgb + soff);
    uint4 k1 = *(const uint4*)(KIMG + imgb + soff + 1024);
    uint4 v0 = *(const uint4*)(VIMG + imgb + soff);
    uint4 v1 = *(const uint4*)(VIMG + imgb + soff + 1024);
    *(uint4*)(KB + soff) = k0;
    *(uint4*)(KB + soff + 1024) = k1;
    *(uint4*)(VB + soff) = v0;
    *(uint4*)(VB + soff + 1024) = v1;
  }
  __syncthreads();

  f32x16 ctx0, ctx1;
#pragma unroll
  for (int i = 0; i < 16; ++i) { ctx0[i] = 0.f; ctx1[i] = 0.f; }
  float* Prow = pout + ((size_t)b*LL + qrow)*LL;
  unsigned bw = 0u;

#pragma unroll 1
  for (int rr = 0; rr < 16; ++rr) {
    const int r0 = rr*2;
    P2ROUND(r0,   0, 1, true,    1);
    P2ROUND(r0+1, 1, 0, (rr<15), 0);
  }

  // ---- ctx epilogue
#pragma unroll
  for (int reg = 0; reg < 16; ++reg) {
    const int q = q0 + p*32 + (reg&3) + 8*(reg>>2) + 4*hi;
    float* cr = ctxout + ((size_t)b*LL + q)*DD;
    cr[sub*64 + c]      = ctx0[reg];
    cr[sub*64 + 32 + c] = ctx1[reg];
  }
}

// ---------- fallback (ws too small): simple correct version ----------
__global__ __launch_bounds__(256) void attn_naive(
    const float* __restrict__ Q, const float* __restrict__ K,
    const float* __restrict__ V, const int* __restrict__ M,
    float* __restrict__ ctx, float* __restrict__ pout)
{
  const int b = blockIdx.x >> 11;
  const int q = blockIdx.x & (LL-1);
  __shared__ float s[LL];
  __shared__ float red[256];
  const int tid = threadIdx.x;
  const float* qp = Q + ((size_t)b*LL + q)*DD;
  for (int kk = tid; kk < LL; kk += 256) {
    const float* kp = K + ((size_t)b*LL + kk)*DD;
    float a = 0.f;
    for (int d = 0; d < DD; ++d) a += qp[d]*kp[d];
    s[kk] = M[((size_t)b*LL + q)*LL + kk] ? a*SCALE : -1e9f;
  }
  __syncthreads();
  float mx = -3e38f;
  for (int kk = tid; kk < LL; kk += 256) mx = fmaxf(mx, s[kk]);
  red[tid] = mx; __syncthreads();
  for (int o = 128; o >= 1; o >>= 1) {
    if (tid < o) red[tid] = fmaxf(red[tid], red[tid+o]);
    __syncthreads();
  }
  const float mrow = red[0]; __syncthreads();
  float sm = 0.f;
  for (int kk = tid; kk < LL; kk += 256) { float e = __expf(s[kk]-mrow); s[kk] = e; sm += e; }
  red[tid] = sm; __syncthreads();
  for (int o = 128; o >= 1; o >>= 1) {
    if (tid < o) red[tid] += red[tid+o];
    __syncthreads();
  }
  const float inv = 1.0f / red[0]; __syncthreads();
  float* prow = pout + ((size_t)b*LL + q)*LL;
  for (int kk = tid; kk < LL; kk += 256) { s[kk] *= inv; prow[kk] = s[kk]; }
  __syncthreads();
  if (tid < DD) {
    float a = 0.f;
    for (int kk = 0; kk < LL; ++kk) a += s[kk]*V[((size_t)b*LL + kk)*DD + tid];
    ctx[((size_t)b*LL + q)*DD + tid] = a;
  }
}

extern "C" void kernel_launch(void* const* d_in, const int* in_sizes, int n_in,
                              void* d_out, int out_size, void* d_ws, size_t ws_size,
                              hipStream_t stream) {
  (void)in_sizes; (void)n_in; (void)out_size;
  const float* Q = (const float*)d_in[0];
  const float* K = (const float*)d_in[1];
  const float* V = (const float*)d_in[2];
  const int*   M = (const int*)d_in[3];
  float* ctx  = (float*)d_out;
  float* pout = ctx + (size_t)BB*LL*DD;
  const size_t IMG = (size_t)BB*NT*16384;      // 8 MB per image
  const size_t WS_NEED = IMG*2;
  if (ws_size >= WS_NEED) {
    unsigned char* kimg = (unsigned char*)d_ws;
    unsigned char* vimg = kimg + IMG;
    hipFuncSetAttribute(reinterpret_cast<const void*>(attn_main),
                        hipFuncAttributeMaxDynamicSharedMemorySize, LDS_MAIN);
    prep_img<<<4096, 256, 0, stream>>>(K, V, kimg, vimg);
    attn_main<<<256, 512, LDS_MAIN, stream>>>(Q, M, kimg, vimg, ctx, pout);
  } else {
    attn_naive<<<BB*LL, 256, 0, stream>>>(Q, K, V, M, ctx, pout);
  }
}

// Round 5
// 202.331 us; speedup vs baseline: 2.2923x; 1.0453x over previous
//
#include <hip/hip_runtime.h>
#include <hip/hip_bf16.h>
#include <hip/hip_fp16.h>

#define BB 16
#define LL 2048
#define DD 128
#define SCALE 0.08838834764831845f
#define CEXP 12.0f
#define NT 32        // k-tiles of 64

typedef _Float16 f16x8 __attribute__((ext_vector_type(8)));
typedef float f32x16 __attribute__((ext_vector_type(16)));

#define MFMA32(a,b,c) __builtin_amdgcn_mfma_f32_32x32x16_f16((a),(b),(c),0,0,0)

// LDS map (main): KB 4x16K | VB 4x16K | PB 16K | RED 1K
#define OFF_KB   0
#define OFF_VB   65536
#define OFF_PB   131072
#define OFF_RED  147456
#define LDS_MAIN 148480

#define WAITVM(N)  asm volatile("s_waitcnt vmcnt(" #N ")" ::: "memory")
#define WAITLGKM0  asm volatile("s_waitcnt lgkmcnt(0)" ::: "memory")
#define MEMFENCE   asm volatile("" ::: "memory")
#define SB0        __builtin_amdgcn_sched_barrier(0)

__device__ __forceinline__ f16x8 as_f16x8(uint4 v){
  union { uint4 u; f16x8 h; } x; x.u = v; return x.h;
}
__device__ __forceinline__ unsigned pkf16(float a, float b){
  __half ha = __float2half_rn(a), hb = __float2half_rn(b);
  return (unsigned)__half_as_ushort(ha) | ((unsigned)__half_as_ushort(hb) << 16);
}
__device__ __forceinline__ unsigned pkrtz(float a, float b){
  union { decltype(__builtin_amdgcn_cvt_pkrtz(0.f, 0.f)) h; unsigned u; } x;
  x.h = __builtin_amdgcn_cvt_pkrtz(a, b);
  return x.u;
}
__device__ __forceinline__ void stage16(const unsigned char* g, char* l){
  __builtin_amdgcn_global_load_lds(
      (const __attribute__((address_space(1))) void*)g,
      (__attribute__((address_space(3))) void*)l, 16, 0, 0);
}
__device__ __forceinline__ void stage2(const unsigned char* g, char* l, int soff){
  stage16(g + soff, l + soff);
  stage16(g + soff + 1024, l + soff + 1024);
}

// ---------- prep: mask->bits | K -> fp16 swizzled k-major image | V -> fp16 swizzled d-major ----------
// K image tile (b,t): byte = klocal*256 + ((gd*16)^((klocal&15)<<4)), gd = d/8
// V image tile (b,t): byte = d*128 + ((gk*16)^((d&7)<<4)), gk covers k 8*gk..+7
__global__ __launch_bounds__(256) void prep_all(
    const float* __restrict__ K, const float* __restrict__ V,
    const int* __restrict__ M,
    unsigned char* __restrict__ kimg, unsigned char* __restrict__ vimg,
    unsigned int* __restrict__ bm)
{
  __shared__ float t[32][65];
  const int bid = blockIdx.x, tid = threadIdx.x;
  if (bid < 8192) {
    const size_t wi = (size_t)bid * 256 + tid;      // word index, 2^21 total
    const int* mp = M + wi * 32;
    unsigned int wrd = 0;
#pragma unroll
    for (int j = 0; j < 8; ++j) {
      int4 v = *(const int4*)(mp + j*4);
      wrd |= (v.x ? 1u : 0u) << (4*j)
          |  (v.y ? 1u : 0u) << (4*j+1)
          |  (v.z ? 1u : 0u) << (4*j+2)
          |  (v.w ? 1u : 0u) << (4*j+3);
    }
    bm[wi] = wrd;
  } else if (bid < 10240) {
    const int G = (bid - 8192)*256 + tid;
    const int b = G >> 15;
    const int k = (G >> 4) & 2047;
    const int gd = G & 15;
    const float* src = K + ((size_t)b*LL + k)*DD + gd*8;
    float4 f0 = *(const float4*)(src);
    float4 f1 = *(const float4*)(src + 4);
    uint4 o;
    o.x = pkf16(f0.x, f0.y); o.y = pkf16(f0.z, f0.w);
    o.z = pkf16(f1.x, f1.y); o.w = pkf16(f1.z, f1.w);
    const size_t base = ((size_t)b*NT + (k>>6))*16384;
    *(uint4*)(kimg + base + (k&63)*256 + ((gd*16) ^ ((k&15)<<4))) = o;
  } else {
    const int t2 = bid - 10240;
    const int b = t2 >> 7;
    const int rem = t2 & 127;
    const int kt = rem >> 2, dt = rem & 3;
    const int k0 = kt*64, d0 = dt*32;
    const int kl = tid >> 2, dq = (tid & 3)*8;
    const float* src = V + ((size_t)b*LL + k0 + kl)*DD + d0 + dq;
    float4 f0 = *(const float4*)(src);
    float4 f1 = *(const float4*)(src + 4);
    t[dq+0][kl] = f0.x; t[dq+1][kl] = f0.y; t[dq+2][kl] = f0.z; t[dq+3][kl] = f0.w;
    t[dq+4][kl] = f1.x; t[dq+5][kl] = f1.y; t[dq+6][kl] = f1.z; t[dq+7][kl] = f1.w;
    __syncthreads();
    const int dl = tid >> 3, kg = tid & 7;
    const int d = d0 + dl;
    uint4 o;
    o.x = pkf16(t[dl][kg*8+0], t[dl][kg*8+1]);
    o.y = pkf16(t[dl][kg*8+2], t[dl][kg*8+3]);
    o.z = pkf16(t[dl][kg*8+4], t[dl][kg*8+5]);
    o.w = pkf16(t[dl][kg*8+6], t[dl][kg*8+7]);
    const size_t base = ((size_t)b*NT + kt)*16384;
    *(uint4*)(vimg + base + d*128 + ((kg*16) ^ ((d&7)<<4))) = o;
  }
}

// QK^T into aA/aB from KB[buf]
#define QKCOMPUTE(BUFIDX) \
  const char* kb = KB + (BUFIDX)*16384 + krow*256; \
  f32x16 aA, aB; \
  _Pragma("unroll") for (int i=0;i<16;++i){aA[i]=0.f;aB[i]=0.f;} \
  _Pragma("unroll") for (int s=0;s<4;++s){ \
    uint4 af = *(const uint4*)(kb + (((s*2+hi)*16) ^ kswz)); \
    aA = MFMA32(as_f16x8(af), as_f16x8(qf[s]), aA); } \
  _Pragma("unroll") for (int s=4;s<8;++s){ \
    uint4 af = *(const uint4*)(kb + (((s*2+hi)*16) ^ kswz)); \
    aB = MFMA32(as_f16x8(af), as_f16x8(qf[s]), aB); }

#define P1BODY(RR) do { \
  WAITVM(6); \
  __builtin_amdgcn_s_barrier(); \
  MEMFENCE; \
  const unsigned bn2 = BMl[2*(((RR)+2)&31)]; \
  SB0; \
  stage2(KIMG + imgb + (size_t)(((RR)+3)&31)*16384, KB + (((RR)+3)&3)*16384, soff); \
  SB0; \
  QKCOMPUTE((RR)&3); \
  const unsigned bwh = bcur >> (4*hi); \
  _Pragma("unroll") for (int i=0;i<16;++i){ \
    const float sv = ((bwh>>((i&3)+8*(i>>2)))&1u) ? fmaf(aA[i]+aB[i], SCALE, -CEXP) : -1.0e9f; \
    psum[i&3] += __expf(sv); } \
  bcur = bn1; bn1 = bn2; \
} while(0)

#define P2BODY(RR, NTOK) do { \
  WAITVM(NTOK); \
  __builtin_amdgcn_s_barrier(); \
  MEMFENCE; \
  const unsigned bn2 = BMl[2*(((RR)+2)&31)]; \
  SB0; \
  stage2(KIMG + imgb + (size_t)(((RR)+3)&31)*16384, KB + (((RR)+3)&3)*16384, soff); \
  stage2(VIMG + imgb + (size_t)(((RR)+3)&31)*16384, VB + (((RR)+3)&3)*16384, soff); \
  SB0; \
  QKCOMPUTE((RR)&3); \
  const unsigned bwh = bcur >> (4*hi); \
  float pv[16]; \
  _Pragma("unroll") for (int i=0;i<16;++i){ \
    const float sv = ((bwh>>((i&3)+8*(i>>2)))&1u) ? fmaf(aA[i]+aB[i], SCALE, -CEXP) : -1.0e9f; \
    pv[i] = __expf(sv) * inv; } \
  { float* pr = Prow + (size_t)(RR)*64 + sub*32 + hi*4; \
    float4 o; \
    o.x=pv[0];  o.y=pv[1];  o.z=pv[2];  o.w=pv[3];  *(float4*)(pr)    = o; \
    o.x=pv[4];  o.y=pv[5];  o.z=pv[6];  o.w=pv[7];  *(float4*)(pr+8)  = o; \
    o.x=pv[8];  o.y=pv[9];  o.z=pv[10]; o.w=pv[11]; *(float4*)(pr+16) = o; \
    o.x=pv[12]; o.y=pv[13]; o.z=pv[14]; o.w=pv[15]; *(float4*)(pr+24) = o; } \
  SB0; \
  { char* pb = PB + p*4096 + sub*2048; \
    uint2 u; \
    u.x = pkrtz(pv[0],pv[1]);   u.y = pkrtz(pv[2],pv[3]);   *(uint2*)(pb + c*16 + hi*8) = u; \
    u.x = pkrtz(pv[4],pv[5]);   u.y = pkrtz(pv[6],pv[7]);   *(uint2*)(pb + (c+32)*16 + hi*8) = u; \
    u.x = pkrtz(pv[8],pv[9]);   u.y = pkrtz(pv[10],pv[11]); *(uint2*)(pb + 1024 + c*16 + hi*8) = u; \
    u.x = pkrtz(pv[12],pv[13]); u.y = pkrtz(pv[14],pv[15]); *(uint2*)(pb + 1024 + (c+32)*16 + hi*8) = u; } \
  WAITLGKM0; \
  __builtin_amdgcn_s_barrier(); \
  MEMFENCE; \
  _Pragma("unroll") for (int s2=0;s2<2;++s2){ \
    _Pragma("unroll") for (int k2=0;k2<2;++k2){ \
      const uint4 afr = *(const uint4*)(PB + p*4096 + s2*2048 + k2*1024 + l*16); \
      const int gix = s2*4 + k2*2 + hi; \
      const int d0v = sub*64 + c; \
      const uint4 b0 = *(const uint4*)(VB + ((RR)&3)*16384 + d0v*128 + ((gix*16) ^ ((d0v&7)<<4))); \
      ctx0 = MFMA32(as_f16x8(afr), as_f16x8(b0), ctx0); \
      const int d1v = sub*64 + 32 + c; \
      const uint4 b1 = *(const uint4*)(VB + ((RR)&3)*16384 + d1v*128 + ((gix*16) ^ ((d1v&7)<<4))); \
      ctx1 = MFMA32(as_f16x8(afr), as_f16x8(b1), ctx1); } } \
  bcur = bn1; bn1 = bn2; \
} while(0)

// ---------- main: 1 WG/CU = (batch, 128 q-rows), 8 waves, two passes ----------
__global__ __launch_bounds__(512) void attn_main(
    const float* __restrict__ Q, const unsigned int* __restrict__ BM,
    const unsigned char* __restrict__ KIMG, const unsigned char* __restrict__ VIMG,
    float* __restrict__ ctxout, float* __restrict__ pout)
{
  extern __shared__ char lds[];
  char* KB = lds + OFF_KB;
  char* VB = lds + OFF_VB;
  char* PB = lds + OFF_PB;
  float* RED = (float*)(lds + OFF_RED);

  const int tid = threadIdx.x;
  const int w = tid >> 6, l = tid & 63;
  const int c = l & 31, hi = l >> 5;
  const int p = w >> 1, sub = w & 1;

  const int bid = blockIdx.x;
  const int xcd = bid & 7, jj = bid >> 3;
  const int b = xcd*2 + (jj >> 4);
  const int q0 = (jj & 15) * 128;
  const int qrow = q0 + p*32 + c;

  // Q fragments (fp16)
  uint4 qf[8];
  const float* qp0 = Q + ((size_t)b*LL + qrow)*DD;
#pragma unroll
  for (int s = 0; s < 8; ++s) {
    const float4 f0 = *(const float4*)(qp0 + s*16 + hi*8);
    const float4 f1 = *(const float4*)(qp0 + s*16 + hi*8 + 4);
    uint4 qv;
    qv.x = pkf16(f0.x, f0.y); qv.y = pkf16(f0.z, f0.w);
    qv.z = pkf16(f1.x, f1.y); qv.w = pkf16(f1.z, f1.w);
    qf[s] = qv;
  }

  const size_t imgb = ((size_t)b * NT) * 16384;
  const int soff = w*2048 + l*16;
  const unsigned int* BMl = BM + ((size_t)b*LL + qrow)*64 + sub;
  const int krow = sub*32 + c;
  const int kswz = (c & 15) << 4;

  // ---------------- PASS 1: row sums of exp(S - CEXP) ----------------
  stage2(KIMG + imgb + 0*16384, KB + 0*16384, soff); SB0;
  unsigned bcur = BMl[0]; SB0;
  stage2(KIMG + imgb + 1*16384, KB + 1*16384, soff); SB0;
  unsigned bn1 = BMl[2]; SB0;
  stage2(KIMG + imgb + 2*16384, KB + 2*16384, soff); SB0;

  float psum[4] = {0.f, 0.f, 0.f, 0.f};
#pragma unroll 1
  for (int r = 0; r < 32; ++r) {
    P1BODY(r);
  }
  float sum = (psum[0] + psum[1]) + (psum[2] + psum[3]);
  sum += __shfl_xor(sum, 32);
  __syncthreads();                       // drains tail dummy stages too
  if (l < 32) RED[(p*2+sub)*32 + c] = sum;
  __syncthreads();
  float tot = RED[(p*2+sub)*32 + c] + RED[(p*2+(1-sub))*32 + c];
  tot = fmaxf(tot, 1e-35f);
  const float inv = 1.0f / tot;
  __syncthreads();

  // ---------------- PASS 2: P = exp(S-CEXP)*inv, write P, ctx = P*V ----------------
  stage2(KIMG + imgb + 0*16384, KB + 0*16384, soff);
  stage2(VIMG + imgb + 0*16384, VB + 0*16384, soff); SB0;
  bcur = BMl[0]; SB0;
  stage2(KIMG + imgb + 1*16384, KB + 1*16384, soff);
  stage2(VIMG + imgb + 1*16384, VB + 1*16384, soff); SB0;
  bn1 = BMl[2]; SB0;
  stage2(KIMG + imgb + 2*16384, KB + 2*16384, soff);
  stage2(VIMG + imgb + 2*16384, VB + 2*16384, soff); SB0;

  f32x16 ctx0, ctx1;
#pragma unroll
  for (int i = 0; i < 16; ++i) { ctx0[i] = 0.f; ctx1[i] = 0.f; }
  float* Prow = pout + ((size_t)b*LL + qrow)*LL;

  P2BODY(0, 10);
  P2BODY(1, 14);
  P2BODY(2, 18);
#pragma unroll 1
  for (int r = 3; r < 32; ++r) {
    P2BODY(r, 22);
  }

  // ---- ctx epilogue
#pragma unroll
  for (int reg = 0; reg < 16; ++reg) {
    const int q = q0 + p*32 + (reg&3) + 8*(reg>>2) + 4*hi;
    float* cr = ctxout + ((size_t)b*LL + q)*DD;
    cr[sub*64 + c]      = ctx0[reg];
    cr[sub*64 + 32 + c] = ctx1[reg];
  }
}

// ---------- fallback (ws too small): simple correct version ----------
__global__ __launch_bounds__(256) void attn_naive(
    const float* __restrict__ Q, const float* __restrict__ K,
    const float* __restrict__ V, const int* __restrict__ M,
    float* __restrict__ ctx, float* __restrict__ pout)
{
  const int b = blockIdx.x >> 11;
  const int q = blockIdx.x & (LL-1);
  __shared__ float s[LL];
  __shared__ float red[256];
  const int tid = threadIdx.x;
  const float* qp = Q + ((size_t)b*LL + q)*DD;
  for (int kk = tid; kk < LL; kk += 256) {
    const float* kp = K + ((size_t)b*LL + kk)*DD;
    float a = 0.f;
    for (int d = 0; d < DD; ++d) a += qp[d]*kp[d];
    s[kk] = M[((size_t)b*LL + q)*LL + kk] ? a*SCALE : -1e9f;
  }
  __syncthreads();
  float mx = -3e38f;
  for (int kk = tid; kk < LL; kk += 256) mx = fmaxf(mx, s[kk]);
  red[tid] = mx; __syncthreads();
  for (int o = 128; o >= 1; o >>= 1) {
    if (tid < o) red[tid] = fmaxf(red[tid], red[tid+o]);
    __syncthreads();
  }
  const float mrow = red[0]; __syncthreads();
  float sm = 0.f;
  for (int kk = tid; kk < LL; kk += 256) { float e = __expf(s[kk]-mrow); s[kk] = e; sm += e; }
  red[tid] = sm; __syncthreads();
  for (int o = 128; o >= 1; o >>= 1) {
    if (tid < o) red[tid] += red[tid+o];
    __syncthreads();
  }
  const float inv = 1.0f / red[0]; __syncthreads();
  float* prow = pout + ((size_t)b*LL + q)*LL;
  for (int kk = tid; kk < LL; kk += 256) { s[kk] *= inv; prow[kk] = s[kk]; }
  __syncthreads();
  if (tid < DD) {
    float a = 0.f;
    for (int kk = 0; kk < LL; ++kk) a += s[kk]*V[((size_t)b*LL + kk)*DD + tid];
    ctx[((size_t)b*LL + q)*DD + tid] = a;
  }
}

extern "C" void kernel_launch(void* const* d_in, const int* in_sizes, int n_in,
                              void* d_out, int out_size, void* d_ws, size_t ws_size,
                              hipStream_t stream) {
  (void)in_sizes; (void)n_in; (void)out_size;
  const float* Q = (const float*)d_in[0];
  const float* K = (const float*)d_in[1];
  const float* V = (const float*)d_in[2];
  const int*   M = (const int*)d_in[3];
  float* ctx  = (float*)d_out;
  float* pout = ctx + (size_t)BB*LL*DD;
  const size_t IMG = (size_t)BB*NT*16384;        // 8 MB per image
  const size_t NBM = (size_t)BB*LL*(LL/32);      // 2.1M words = 8 MB
  const size_t WS_NEED = IMG*2 + NBM*4;
  if (ws_size >= WS_NEED) {
    unsigned char* kimg = (unsigned char*)d_ws;
    unsigned char* vimg = kimg + IMG;
    unsigned int*  bmw  = (unsigned int*)(vimg + IMG);
    hipFuncSetAttribute(reinterpret_cast<const void*>(attn_main),
                        hipFuncAttributeMaxDynamicSharedMemorySize, LDS_MAIN);
    prep_all<<<12288, 256, 0, stream>>>(K, V, M, kimg, vimg, bmw);
    attn_main<<<256, 512, LDS_MAIN, stream>>>(Q, bmw, kimg, vimg, ctx, pout);
  } else {
    attn_naive<<<BB*LL, 256, 0, stream>>>(Q, K, V, M, ctx, pout);
  }
}